// Round 2
// baseline (905.470 us; speedup 1.0000x reference)
//
#include <hip/hip_runtime.h>
#include <cstdint>

#define R_ROWS 32768
#define F1 512
#define F2 2048
#define NOUT 512

typedef __bf16 bf16x8 __attribute__((ext_vector_type(8)));
typedef float f32x4 __attribute__((ext_vector_type(4)));

__device__ __forceinline__ float bf2f(uint16_t b) {
  union { uint32_t u; float f; } v; v.u = ((uint32_t)b) << 16; return v.f;
}
__device__ __forceinline__ uint16_t f2bf(float f) {
  union { float f; uint32_t u; } v; v.f = f;
  uint32_t u = v.u;
  return (uint16_t)((u + 0x7fffu + ((u >> 16) & 1u)) >> 16);
}

union U4 { uint4 v; uint16_t s[8]; };

// ---- dtype sniffer: bf16 N(0,1) data has sane exponent fields in EVERY uint16;
// fp32 data reinterpreted as uint16 has ~79% insane exponents in the low halves.
__global__ void sniff_kernel(const uint16_t* x, int* flag) {
  if (threadIdx.x == 0) {
    int bad = 0;
    for (int i = 0; i < 64; ++i) {
      uint32_t e = (x[i] >> 7) & 0xFFu;
      if (e != 0u && (e < 90u || e > 141u)) bad++;
    }
    *flag = (bad >= 8) ? 1 : 0;  // 1 = fp32 world, 0 = bf16 world
  }
}

// ---- fp32 -> bf16 convert (fp32 world only; guarded to avoid OOB reads in bf16 world)
__global__ void conv_f32_bf16(const float* in, uint16_t* out, int n, const int* flag) {
  if (*flag != 1) return;
  int i = blockIdx.x * blockDim.x + threadIdx.x;
  if (i < n) out[i] = f2bf(in[i]);
}

// ---- prep: diag = softplus(d)+2, tl = tanh(l), tu = tanh(u) (tu[F-1]=0)
// fact layout per matrix (floats): [diag | tl | tu | w | invb], each F entries.
template<bool INF32>
__global__ void prep_parallel(const void* d1, const void* l1, const void* u1,
                              const void* d2, const void* l2, const void* u2,
                              float* f1, float* f2, const int* flag, int mode) {
  if (*flag != mode) return;
  int i = blockIdx.x * blockDim.x + threadIdx.x;
  if (i < F1) {
    float dv = INF32 ? ((const float*)d1)[i] : bf2f(((const uint16_t*)d1)[i]);
    f1[i] = log1pf(expf(dv)) + 2.0f;
    float lv = (i < F1 - 1) ? (INF32 ? ((const float*)l1)[i] : bf2f(((const uint16_t*)l1)[i])) : 0.0f;
    float uv = (i < F1 - 1) ? (INF32 ? ((const float*)u1)[i] : bf2f(((const uint16_t*)u1)[i])) : 0.0f;
    f1[F1 + i]   = (i < F1 - 1) ? tanhf(lv) : 0.0f;
    f1[2*F1 + i] = (i < F1 - 1) ? tanhf(uv) : 0.0f;
  }
  int j = i - F1;
  if (j >= 0 && j < F2) {
    float dv = INF32 ? ((const float*)d2)[j] : bf2f(((const uint16_t*)d2)[j]);
    f2[j] = log1pf(expf(dv)) + 2.0f;
    float lv = (j < F2 - 1) ? (INF32 ? ((const float*)l2)[j] : bf2f(((const uint16_t*)l2)[j])) : 0.0f;
    float uv = (j < F2 - 1) ? (INF32 ? ((const float*)u2)[j] : bf2f(((const uint16_t*)u2)[j])) : 0.0f;
    f2[F2 + j]   = (j < F2 - 1) ? tanhf(lv) : 0.0f;
    f2[2*F2 + j] = (j < F2 - 1) ? tanhf(uv) : 0.0f;
  }
}

// Sequential Thomas factorization: w_i = tl[i-1]/b'_{i-1}; b'_i = diag_i - w_i*tu[i-1].
__global__ void prep_factor(float* f1, float* f2) {
  int lane = threadIdx.x;
  if (lane < 2) {
    float* base = lane ? f2 : f1;
    int F = lane ? F2 : F1;
    const float* diag = base;
    const float* tl   = base + F;
    const float* tu   = base + 2 * F;
    float* fw  = base + 3 * F;
    float* fib = base + 4 * F;
    float b = diag[0];
    float ib = 1.0f / b;
    fw[0] = 0.0f; fib[0] = ib;
    for (int i = 1; i < F; ++i) {
      float w = tl[i - 1] * ib;
      b = diag[i] - w * tu[i - 1];
      ib = 1.0f / b;
      fw[i] = w; fib[i] = ib;
    }
  }
}

// ---- per-row Thomas solve; input bf16 or fp32, intermediates/output bf16, fp32 recurrence.
// mode < 0: always run. X and Y may alias when input is bf16.
template<int F, bool INF32>
__launch_bounds__(64)
__global__ void solve_kernel(const void* X, uint16_t* Y, const float* fact,
                             const int* flag, int mode) {
  if (mode >= 0 && *flag != mode) return;
  __shared__ float sfw[F], sib[F], stu[F];
  for (int i = threadIdx.x; i < F; i += 64) {
    sfw[i] = fact[3 * F + i];
    sib[i] = fact[4 * F + i];
    stu[i] = fact[2 * F + i];
  }
  __syncthreads();
  size_t row = (size_t)blockIdx.x * 64 + threadIdx.x;
  uint16_t* yr = Y + row * F;
  float dp = 0.0f;
  for (int c = 0; c < F; c += 8) {
    float xv[8];
    if (INF32) {
      const float4* xp = (const float4*)((const float*)X + row * F + c);
      float4 v0 = xp[0], v1 = xp[1];
      xv[0]=v0.x; xv[1]=v0.y; xv[2]=v0.z; xv[3]=v0.w;
      xv[4]=v1.x; xv[5]=v1.y; xv[6]=v1.z; xv[7]=v1.w;
    } else {
      U4 in; in.v = *(const uint4*)((const uint16_t*)X + row * F + c);
      #pragma unroll
      for (int j = 0; j < 8; ++j) xv[j] = bf2f(in.s[j]);
    }
    U4 out;
    #pragma unroll
    for (int j = 0; j < 8; ++j) {
      dp = fmaf(-sfw[c + j], dp, xv[j]);
      out.s[j] = f2bf(dp);
    }
    *(uint4*)(yr + c) = out.v;
  }
  float yn = 0.0f;
  for (int c = F - 8; c >= 0; c -= 8) {
    U4 in; in.v = *(const uint4*)(yr + c);
    U4 out;
    #pragma unroll
    for (int j = 7; j >= 0; --j) {
      float v = fmaf(-stu[c + j], yn, bf2f(in.s[j])) * sib[c + j];
      out.s[j] = f2bf(v);
      yn = v;
    }
    *(uint4*)(yr + c) = out.v;
  }
}

// ---- bf16 GEMM, C[m][n] = sum_k A[m][k]*Bw[n][k] (both K-major, bf16), m97 structure.
__device__ __forceinline__ void gl_lds16(const uint16_t* g, uint16_t* l) {
  __builtin_amdgcn_global_load_lds((const __attribute__((address_space(1))) void*)g,
                                   (__attribute__((address_space(3))) void*)l, 16, 0, 0);
}

template<bool RELU, bool OUTF32>
__launch_bounds__(256, 1)
__global__ void gemm_bt(const uint16_t* __restrict__ A, const uint16_t* __restrict__ Bw,
                        const uint16_t* __restrict__ bias, void* __restrict__ Cout,
                        int N, int K, const int* flag, int mode) {
  if (*flag != mode) return;
  __shared__ uint16_t As[128 * 32];
  __shared__ uint16_t Bs[128 * 32];
  const int tid  = threadIdx.x;
  const int lane = tid & 63;
  const int wv   = tid >> 6;
  const int wm   = (wv >> 1) * 64;
  const int wn   = (wv & 1) * 64;
  const int rowA0 = blockIdx.x * 128;
  const int rowB0 = blockIdx.y * 128;
  const int r  = tid >> 2;
  const int kc = (tid & 3) * 8;
  const uint16_t* agp0 = A  + (size_t)(rowA0 + r) * K + kc;
  const uint16_t* agp1 = agp0 + (size_t)64 * K;
  const uint16_t* bgp0 = Bw + (size_t)(rowB0 + r) * K + kc;
  const uint16_t* bgp1 = bgp0 + (size_t)64 * K;
  const int wbase = (tid & ~63) * 8;
  uint16_t* asl0 = As + wbase;
  uint16_t* asl1 = As + 2048 + wbase;
  uint16_t* bsl0 = Bs + wbase;
  uint16_t* bsl1 = Bs + 2048 + wbase;

  const int aoff = (wm + (lane & 15)) * 32 + (lane >> 4) * 8;
  const int boff = (wn + (lane & 15)) * 32 + (lane >> 4) * 8;

  f32x4 acc[4][4] = {};

  for (int kt = 0; kt < K; kt += 32) {
    gl_lds16(agp0 + kt, asl0);
    gl_lds16(agp1 + kt, asl1);
    gl_lds16(bgp0 + kt, bsl0);
    gl_lds16(bgp1 + kt, bsl1);
    __syncthreads();
    bf16x8 af[4], bfr[4];
    #pragma unroll
    for (int i = 0; i < 4; ++i) af[i]  = *(const bf16x8*)(As + aoff + i * 512);
    #pragma unroll
    for (int j = 0; j < 4; ++j) bfr[j] = *(const bf16x8*)(Bs + boff + j * 512);
    #pragma unroll
    for (int i = 0; i < 4; ++i)
      #pragma unroll
      for (int j = 0; j < 4; ++j)
        acc[i][j] = __builtin_amdgcn_mfma_f32_16x16x32_bf16(af[i], bfr[j], acc[i][j], 0, 0, 0);
    __syncthreads();
  }

  // C/D layout: col = lane&15, row = (lane>>4)*4 + reg
  const int ccol = lane & 15;
  const int crow = (lane >> 4) * 4;
  #pragma unroll
  for (int j = 0; j < 4; ++j) {
    int col = rowB0 + wn + j * 16 + ccol;
    float bv = bf2f(bias[col]);
    #pragma unroll
    for (int i = 0; i < 4; ++i) {
      int row0 = rowA0 + wm + i * 16 + crow;
      #pragma unroll
      for (int rr = 0; rr < 4; ++rr) {
        float v = acc[i][j][rr] + bv;
        if (RELU) v = fmaxf(v, 0.0f);
        size_t idx = (size_t)(row0 + rr) * N + col;
        if (OUTF32) ((float*)Cout)[idx]    = v;
        else        ((uint16_t*)Cout)[idx] = f2bf(v);
      }
    }
  }
}

extern "C" void kernel_launch(void* const* d_in, const int* in_sizes, int n_in,
                              void* d_out, int out_size, void* d_ws, size_t ws_size,
                              hipStream_t stream) {
  const void* x  = d_in[0];
  const void* d1 = d_in[1];
  const void* l1 = d_in[2];
  const void* u1 = d_in[3];
  const void* W1 = d_in[4];
  const void* b1 = d_in[5];
  const void* d2 = d_in[6];
  const void* l2 = d_in[7];
  const void* u2 = d_in[8];
  const void* W2 = d_in[9];
  const void* b2 = d_in[10];

  char* ws = (char*)d_ws;
  int*      flag = (int*)ws;
  float*    f1   = (float*)(ws + 256);
  float*    f2   = (float*)(ws + (64 << 10));
  uint16_t* b1b  = (uint16_t*)(ws + (128 << 10));
  uint16_t* b2b  = (uint16_t*)(ws + (136 << 10));
  uint16_t* W1b  = (uint16_t*)(ws + (1 << 20));                     // 2 MB
  uint16_t* W2b  = (uint16_t*)(ws + (3 << 20));                     // 2 MB
  uint16_t* A1   = (uint16_t*)(ws + ((size_t)8 << 20));             // 32 MB
  uint16_t* H1   = (uint16_t*)(ws + ((size_t)40 << 20));            // 128 MB, ends at 168 MB

  sniff_kernel<<<1, 64, 0, stream>>>((const uint16_t*)x, flag);

  // fp32-world weight/bias conversion (no-op + no reads in bf16 world)
  conv_f32_bf16<<<(F2 * F1 + 255) / 256, 256, 0, stream>>>((const float*)W1, W1b, F2 * F1, flag);
  conv_f32_bf16<<<(NOUT * F2 + 255) / 256, 256, 0, stream>>>((const float*)W2, W2b, NOUT * F2, flag);
  conv_f32_bf16<<<(F2 + 255) / 256, 256, 0, stream>>>((const float*)b1, b1b, F2, flag);
  conv_f32_bf16<<<(NOUT + 255) / 256, 256, 0, stream>>>((const float*)b2, b2b, NOUT, flag);

  prep_parallel<false><<<(F1 + F2 + 255) / 256, 256, 0, stream>>>(d1, l1, u1, d2, l2, u2, f1, f2, flag, 0);
  prep_parallel<true ><<<(F1 + F2 + 255) / 256, 256, 0, stream>>>(d1, l1, u1, d2, l2, u2, f1, f2, flag, 1);
  prep_factor<<<1, 64, 0, stream>>>(f1, f2);

  solve_kernel<F1, false><<<R_ROWS / 64, 64, 0, stream>>>(x, A1, f1, flag, 0);
  solve_kernel<F1, true ><<<R_ROWS / 64, 64, 0, stream>>>(x, A1, f1, flag, 1);

  gemm_bt<true, false><<<dim3(R_ROWS / 128, F2 / 128), 256, 0, stream>>>(
      A1, (const uint16_t*)W1, (const uint16_t*)b1, H1, F2, F1, flag, 0);
  gemm_bt<true, false><<<dim3(R_ROWS / 128, F2 / 128), 256, 0, stream>>>(
      A1, W1b, b1b, H1, F2, F1, flag, 1);

  solve_kernel<F2, false><<<R_ROWS / 64, 64, 0, stream>>>(H1, H1, f2, flag, -1);

  gemm_bt<false, false><<<dim3(R_ROWS / 128, NOUT / 128), 256, 0, stream>>>(
      H1, (const uint16_t*)W2, (const uint16_t*)b2, d_out, NOUT, F2, flag, 0);
  gemm_bt<false, true ><<<dim3(R_ROWS / 128, NOUT / 128), 256, 0, stream>>>(
      H1, W2b, b2b, d_out, NOUT, F2, flag, 1);
}

// Round 3
// 662.330 us; speedup vs baseline: 1.3671x; 1.3671x over previous
//
#include <hip/hip_runtime.h>
#include <cstdint>

#define R_ROWS 32768
#define F1 512
#define F2 2048
#define NOUT 512

typedef __bf16 bf16x8 __attribute__((ext_vector_type(8)));
typedef float f32x4 __attribute__((ext_vector_type(4)));

__device__ __forceinline__ float bf2f(uint16_t b) {
  union { uint32_t u; float f; } v; v.u = ((uint32_t)b) << 16; return v.f;
}
__device__ __forceinline__ uint16_t f2bf(float f) {
  union { float f; uint32_t u; } v; v.f = f;
  uint32_t u = v.u;
  return (uint16_t)((u + 0x7fffu + ((u >> 16) & 1u)) >> 16);
}

union U4 { uint4 v; uint16_t s[8]; };

// ---- dtype sniffer: bf16 N(0,1) data has sane exponent fields in EVERY uint16;
// fp32 data reinterpreted as uint16 has ~79% insane exponents in the low halves.
__global__ void sniff_kernel(const uint16_t* x, int* flag) {
  if (threadIdx.x == 0) {
    int bad = 0;
    for (int i = 0; i < 64; ++i) {
      uint32_t e = (x[i] >> 7) & 0xFFu;
      if (e != 0u && (e < 90u || e > 141u)) bad++;
    }
    *flag = (bad >= 8) ? 1 : 0;  // 1 = fp32 world, 0 = bf16 world
  }
}

// ---- fp32 world only: convert W1, W2, b1, b2 to bf16 in one launch, 4 elems/thread.
__global__ void conv_all(const float* W1, const float* W2, const float* b1, const float* b2,
                         uint16_t* W1b, uint16_t* W2b, uint16_t* b1b, uint16_t* b2b,
                         const int* flag) {
  if (*flag != 1) return;
  const int NW = F2 * F1;                  // 1048576 (both W1 and W2)
  int q = blockIdx.x * blockDim.x + threadIdx.x;
  const float* src; uint16_t* dst; int base;
  if (q < NW / 4)                       { src = W1; dst = W1b; base = q; }
  else if (q < NW / 2)                  { src = W2; dst = W2b; base = q - NW / 4; }
  else if (q < NW / 2 + F2 / 4)         { src = b1; dst = b1b; base = q - NW / 2; }
  else if (q < NW / 2 + F2 / 4 + NOUT/4){ src = b2; dst = b2b; base = q - NW / 2 - F2 / 4; }
  else return;
  float4 v = ((const float4*)src)[base];
  ushort4 o;
  o.x = f2bf(v.x); o.y = f2bf(v.y); o.z = f2bf(v.z); o.w = f2bf(v.w);
  ((ushort4*)dst)[base] = o;
}

// ---- fused prep: softplus/tanh in parallel into LDS, sequential Thomas factorization
// from LDS (rcp chain, ~16 cyc/iter), parallel writeback of [tu | w | invb].
// fact global layout per matrix (floats): [diag | tl | tu | w | invb] — only 2F..5F written/used.
template<bool INF32>
__launch_bounds__(256)
__global__ void prep_fused(const void* d1, const void* l1, const void* u1,
                           const void* d2, const void* l2, const void* u2,
                           float* f1, float* f2, const int* flag, int mode) {
  if (*flag != mode) return;
  const int F = blockIdx.x ? F2 : F1;
  float* base = blockIdx.x ? f2 : f1;
  const void* dp = blockIdx.x ? d2 : d1;
  const void* lp = blockIdx.x ? l2 : l1;
  const void* up = blockIdx.x ? u2 : u1;

  __shared__ float sdiag[F2], stl[F2], stu[F2], sfw[F2], sib[F2];

  for (int i = threadIdx.x; i < F; i += 256) {
    float dv = INF32 ? ((const float*)dp)[i] : bf2f(((const uint16_t*)dp)[i]);
    sdiag[i] = log1pf(expf(dv)) + 2.0f;
    bool in = i < F - 1;
    float lv = in ? (INF32 ? ((const float*)lp)[i] : bf2f(((const uint16_t*)lp)[i])) : 0.0f;
    float uv = in ? (INF32 ? ((const float*)up)[i] : bf2f(((const uint16_t*)up)[i])) : 0.0f;
    stl[i] = in ? tanhf(lv) : 0.0f;
    stu[i] = in ? tanhf(uv) : 0.0f;
  }
  __syncthreads();
  if (threadIdx.x == 0) {
    float ib = __builtin_amdgcn_rcpf(sdiag[0]);
    sfw[0] = 0.0f; sib[0] = ib;
    #pragma unroll 8
    for (int i = 1; i < F; ++i) {
      float w = stl[i - 1] * ib;
      float b = fmaf(-w, stu[i - 1], sdiag[i]);
      ib = __builtin_amdgcn_rcpf(b);
      sfw[i] = w; sib[i] = ib;
    }
  }
  __syncthreads();
  for (int i = threadIdx.x; i < F; i += 256) {
    base[2 * F + i] = stu[i];
    base[3 * F + i] = sfw[i];
    base[4 * F + i] = sib[i];
  }
}

// ---- per-row Thomas solve; input bf16 or fp32, intermediates/output bf16, fp32 recurrence.
// mode < 0: always run. X and Y may alias when input is bf16.
template<int F, bool INF32>
__launch_bounds__(64)
__global__ void solve_kernel(const void* X, uint16_t* Y, const float* fact,
                             const int* flag, int mode) {
  if (mode >= 0 && *flag != mode) return;
  __shared__ float sfw[F], sib[F], stu[F];
  for (int i = threadIdx.x; i < F; i += 64) {
    sfw[i] = fact[3 * F + i];
    sib[i] = fact[4 * F + i];
    stu[i] = fact[2 * F + i];
  }
  __syncthreads();
  size_t row = (size_t)blockIdx.x * 64 + threadIdx.x;
  uint16_t* yr = Y + row * F;
  float dp = 0.0f;
  for (int c = 0; c < F; c += 8) {
    float xv[8];
    if (INF32) {
      const float4* xp = (const float4*)((const float*)X + row * F + c);
      float4 v0 = xp[0], v1 = xp[1];
      xv[0]=v0.x; xv[1]=v0.y; xv[2]=v0.z; xv[3]=v0.w;
      xv[4]=v1.x; xv[5]=v1.y; xv[6]=v1.z; xv[7]=v1.w;
    } else {
      U4 in; in.v = *(const uint4*)((const uint16_t*)X + row * F + c);
      #pragma unroll
      for (int j = 0; j < 8; ++j) xv[j] = bf2f(in.s[j]);
    }
    U4 out;
    #pragma unroll
    for (int j = 0; j < 8; ++j) {
      dp = fmaf(-sfw[c + j], dp, xv[j]);
      out.s[j] = f2bf(dp);
    }
    *(uint4*)(yr + c) = out.v;
  }
  float yn = 0.0f;
  for (int c = F - 8; c >= 0; c -= 8) {
    U4 in; in.v = *(const uint4*)(yr + c);
    U4 out;
    #pragma unroll
    for (int j = 7; j >= 0; --j) {
      float v = fmaf(-stu[c + j], yn, bf2f(in.s[j])) * sib[c + j];
      out.s[j] = f2bf(v);
      yn = v;
    }
    *(uint4*)(yr + c) = out.v;
  }
}

// ---- bf16 GEMM, C[m][n] = sum_k A[m][k]*Bw[n][k] (both K-major, bf16), m97 structure.
__device__ __forceinline__ void gl_lds16(const uint16_t* g, uint16_t* l) {
  __builtin_amdgcn_global_load_lds((const __attribute__((address_space(1))) void*)g,
                                   (__attribute__((address_space(3))) void*)l, 16, 0, 0);
}

template<bool RELU, bool OUTF32>
__launch_bounds__(256, 1)
__global__ void gemm_bt(const uint16_t* __restrict__ A, const uint16_t* __restrict__ Bw,
                        const uint16_t* __restrict__ bias, void* __restrict__ Cout,
                        int N, int K, const int* flag, int mode) {
  if (*flag != mode) return;
  __shared__ uint16_t As[128 * 32];
  __shared__ uint16_t Bs[128 * 32];
  const int tid  = threadIdx.x;
  const int lane = tid & 63;
  const int wv   = tid >> 6;
  const int wm   = (wv >> 1) * 64;
  const int wn   = (wv & 1) * 64;
  const int rowA0 = blockIdx.x * 128;
  const int rowB0 = blockIdx.y * 128;
  const int r  = tid >> 2;
  const int kc = (tid & 3) * 8;
  const uint16_t* agp0 = A  + (size_t)(rowA0 + r) * K + kc;
  const uint16_t* agp1 = agp0 + (size_t)64 * K;
  const uint16_t* bgp0 = Bw + (size_t)(rowB0 + r) * K + kc;
  const uint16_t* bgp1 = bgp0 + (size_t)64 * K;
  const int wbase = (tid & ~63) * 8;
  uint16_t* asl0 = As + wbase;
  uint16_t* asl1 = As + 2048 + wbase;
  uint16_t* bsl0 = Bs + wbase;
  uint16_t* bsl1 = Bs + 2048 + wbase;

  const int aoff = (wm + (lane & 15)) * 32 + (lane >> 4) * 8;
  const int boff = (wn + (lane & 15)) * 32 + (lane >> 4) * 8;

  f32x4 acc[4][4] = {};

  for (int kt = 0; kt < K; kt += 32) {
    gl_lds16(agp0 + kt, asl0);
    gl_lds16(agp1 + kt, asl1);
    gl_lds16(bgp0 + kt, bsl0);
    gl_lds16(bgp1 + kt, bsl1);
    __syncthreads();
    bf16x8 af[4], bfr[4];
    #pragma unroll
    for (int i = 0; i < 4; ++i) af[i]  = *(const bf16x8*)(As + aoff + i * 512);
    #pragma unroll
    for (int j = 0; j < 4; ++j) bfr[j] = *(const bf16x8*)(Bs + boff + j * 512);
    #pragma unroll
    for (int i = 0; i < 4; ++i)
      #pragma unroll
      for (int j = 0; j < 4; ++j)
        acc[i][j] = __builtin_amdgcn_mfma_f32_16x16x32_bf16(af[i], bfr[j], acc[i][j], 0, 0, 0);
    __syncthreads();
  }

  // C/D layout: col = lane&15, row = (lane>>4)*4 + reg
  const int ccol = lane & 15;
  const int crow = (lane >> 4) * 4;
  #pragma unroll
  for (int j = 0; j < 4; ++j) {
    int col = rowB0 + wn + j * 16 + ccol;
    float bv = bf2f(bias[col]);
    #pragma unroll
    for (int i = 0; i < 4; ++i) {
      int row0 = rowA0 + wm + i * 16 + crow;
      #pragma unroll
      for (int rr = 0; rr < 4; ++rr) {
        float v = acc[i][j][rr] + bv;
        if (RELU) v = fmaxf(v, 0.0f);
        size_t idx = (size_t)(row0 + rr) * N + col;
        if (OUTF32) ((float*)Cout)[idx]    = v;
        else        ((uint16_t*)Cout)[idx] = f2bf(v);
      }
    }
  }
}

extern "C" void kernel_launch(void* const* d_in, const int* in_sizes, int n_in,
                              void* d_out, int out_size, void* d_ws, size_t ws_size,
                              hipStream_t stream) {
  const void* x  = d_in[0];
  const void* d1 = d_in[1];
  const void* l1 = d_in[2];
  const void* u1 = d_in[3];
  const void* W1 = d_in[4];
  const void* b1 = d_in[5];
  const void* d2 = d_in[6];
  const void* l2 = d_in[7];
  const void* u2 = d_in[8];
  const void* W2 = d_in[9];
  const void* b2 = d_in[10];

  char* ws = (char*)d_ws;
  int*      flag = (int*)ws;
  float*    f1   = (float*)(ws + 256);
  float*    f2   = (float*)(ws + (64 << 10));
  uint16_t* b1b  = (uint16_t*)(ws + (128 << 10));
  uint16_t* b2b  = (uint16_t*)(ws + (136 << 10));
  uint16_t* W1b  = (uint16_t*)(ws + (1 << 20));                     // 2 MB
  uint16_t* W2b  = (uint16_t*)(ws + (3 << 20));                     // 2 MB
  uint16_t* A1   = (uint16_t*)(ws + ((size_t)8 << 20));             // 32 MB
  uint16_t* H1   = (uint16_t*)(ws + ((size_t)40 << 20));            // 128 MB, ends at 168 MB

  sniff_kernel<<<1, 64, 0, stream>>>((const uint16_t*)x, flag);

  // fp32-world weight/bias conversion (single launch; no-op + no reads in bf16 world)
  {
    int quads = (F2 * F1) / 2 + F2 / 4 + NOUT / 4;
    conv_all<<<(quads + 255) / 256, 256, 0, stream>>>(
        (const float*)W1, (const float*)W2, (const float*)b1, (const float*)b2,
        W1b, W2b, b1b, b2b, flag);
  }

  prep_fused<false><<<2, 256, 0, stream>>>(d1, l1, u1, d2, l2, u2, f1, f2, flag, 0);
  prep_fused<true ><<<2, 256, 0, stream>>>(d1, l1, u1, d2, l2, u2, f1, f2, flag, 1);

  solve_kernel<F1, false><<<R_ROWS / 64, 64, 0, stream>>>(x, A1, f1, flag, 0);
  solve_kernel<F1, true ><<<R_ROWS / 64, 64, 0, stream>>>(x, A1, f1, flag, 1);

  gemm_bt<true, false><<<dim3(R_ROWS / 128, F2 / 128), 256, 0, stream>>>(
      A1, (const uint16_t*)W1, (const uint16_t*)b1, H1, F2, F1, flag, 0);
  gemm_bt<true, false><<<dim3(R_ROWS / 128, F2 / 128), 256, 0, stream>>>(
      A1, W1b, b1b, H1, F2, F1, flag, 1);

  solve_kernel<F2, false><<<R_ROWS / 64, 64, 0, stream>>>(H1, H1, f2, flag, -1);

  gemm_bt<false, false><<<dim3(R_ROWS / 128, NOUT / 128), 256, 0, stream>>>(
      H1, (const uint16_t*)W2, (const uint16_t*)b2, d_out, NOUT, F2, flag, 0);
  gemm_bt<false, true ><<<dim3(R_ROWS / 128, NOUT / 128), 256, 0, stream>>>(
      H1, W2b, b2b, d_out, NOUT, F2, flag, 1);
}

// Round 4
// 522.560 us; speedup vs baseline: 1.7328x; 1.2675x over previous
//
#include <hip/hip_runtime.h>
#include <cstdint>

#define R_ROWS 32768
#define F1 512
#define F2 2048
#define NOUT 512

typedef __bf16 bf16x8 __attribute__((ext_vector_type(8)));
typedef float f32x4 __attribute__((ext_vector_type(4)));

__device__ __forceinline__ float bf2f(uint16_t b) {
  union { uint32_t u; float f; } v; v.u = ((uint32_t)b) << 16; return v.f;
}
__device__ __forceinline__ uint16_t f2bf(float f) {
  union { float f; uint32_t u; } v; v.f = f;
  uint32_t u = v.u;
  return (uint16_t)((u + 0x7fffu + ((u >> 16) & 1u)) >> 16);
}

union U4 { uint4 v; uint16_t s[8]; };

// ---- dtype sniffer: bf16 N(0,1) data has sane exponent fields in EVERY uint16;
// fp32 data reinterpreted as uint16 has ~79% insane exponents in the low halves.
__global__ void sniff_kernel(const uint16_t* x, int* flag) {
  if (threadIdx.x == 0) {
    int bad = 0;
    for (int i = 0; i < 64; ++i) {
      uint32_t e = (x[i] >> 7) & 0xFFu;
      if (e != 0u && (e < 90u || e > 141u)) bad++;
    }
    *flag = (bad >= 8) ? 1 : 0;  // 1 = fp32 world, 0 = bf16 world
  }
}

// ---- fp32 world only: convert W1, W2, b1, b2 to bf16 in one launch, 4 elems/thread.
__global__ void conv_all(const float* W1, const float* W2, const float* b1, const float* b2,
                         uint16_t* W1b, uint16_t* W2b, uint16_t* b1b, uint16_t* b2b,
                         const int* flag) {
  if (*flag != 1) return;
  const int NW = F2 * F1;                  // 1048576 (both W1 and W2)
  int q = blockIdx.x * blockDim.x + threadIdx.x;
  const float* src; uint16_t* dst; int base;
  if (q < NW / 4)                       { src = W1; dst = W1b; base = q; }
  else if (q < NW / 2)                  { src = W2; dst = W2b; base = q - NW / 4; }
  else if (q < NW / 2 + F2 / 4)         { src = b1; dst = b1b; base = q - NW / 2; }
  else if (q < NW / 2 + F2 / 4 + NOUT/4){ src = b2; dst = b2b; base = q - NW / 2 - F2 / 4; }
  else return;
  float4 v = ((const float4*)src)[base];
  ushort4 o;
  o.x = f2bf(v.x); o.y = f2bf(v.y); o.z = f2bf(v.z); o.w = f2bf(v.w);
  ((ushort4*)dst)[base] = o;
}

// ---- fused prep: softplus/tanh in parallel into LDS, sequential Thomas factorization
// from LDS (rcp chain), parallel writeback of [tu | w | invb | bk=tu*invb].
// fact global layout per matrix (floats): [diag | tl | tu | w | invb | bk].
template<bool INF32>
__launch_bounds__(256)
__global__ void prep_fused(const void* d1, const void* l1, const void* u1,
                           const void* d2, const void* l2, const void* u2,
                           float* f1, float* f2, const int* flag, int mode) {
  if (*flag != mode) return;
  const int F = blockIdx.x ? F2 : F1;
  float* base = blockIdx.x ? f2 : f1;
  const void* dp = blockIdx.x ? d2 : d1;
  const void* lp = blockIdx.x ? l2 : l1;
  const void* up = blockIdx.x ? u2 : u1;

  __shared__ float sdiag[F2], stl[F2], stu[F2], sfw[F2], sib[F2];

  for (int i = threadIdx.x; i < F; i += 256) {
    float dv = INF32 ? ((const float*)dp)[i] : bf2f(((const uint16_t*)dp)[i]);
    sdiag[i] = log1pf(expf(dv)) + 2.0f;
    bool in = i < F - 1;
    float lv = in ? (INF32 ? ((const float*)lp)[i] : bf2f(((const uint16_t*)lp)[i])) : 0.0f;
    float uv = in ? (INF32 ? ((const float*)up)[i] : bf2f(((const uint16_t*)up)[i])) : 0.0f;
    stl[i] = in ? tanhf(lv) : 0.0f;
    stu[i] = in ? tanhf(uv) : 0.0f;
  }
  __syncthreads();
  if (threadIdx.x == 0) {
    float ib = __builtin_amdgcn_rcpf(sdiag[0]);
    sfw[0] = 0.0f; sib[0] = ib;
    #pragma unroll 8
    for (int i = 1; i < F; ++i) {
      float w = stl[i - 1] * ib;
      float b = fmaf(-w, stu[i - 1], sdiag[i]);
      ib = __builtin_amdgcn_rcpf(b);
      sfw[i] = w; sib[i] = ib;
    }
  }
  __syncthreads();
  for (int i = threadIdx.x; i < F; i += 256) {
    base[2 * F + i] = stu[i];
    base[3 * F + i] = sfw[i];
    base[4 * F + i] = sib[i];
    base[5 * F + i] = stu[i] * sib[i];
  }
}

// ---- chunk-parallel Thomas solve. Lane owns 32 elements of F; 16-element halo
// warm-up exploits the recurrence's exponential decay (|coef| <= ~0.03 ->
// truncation < 1e-22 rel). dp stays fp32 in registers; backward halo dp comes
// from lane+1 via shfl. LDS coeffs swizzled (k + k/32) to kill the 64-way
// same-bank pattern that stride-32 indexing would cause.
// In-place X==Y is safe: halo interactions are intra-wave (loads precede stores
// in the lockstep stream). mode < 0: always run.
template<int F, bool INF32>
__launch_bounds__(256)
__global__ void solve_fused(const void* X, uint16_t* Y, const float* fact,
                            const int* flag, int mode) {
  if (mode >= 0 && *flag != mode) return;
  constexpr int LPR = F / 32;                  // lanes per row (16 or 64)
  constexpr int FP = F + (F >> 5);             // padded coeff size
  __shared__ float sfw[FP], sib[FP], sbk[FP];
  for (int i = threadIdx.x; i < F; i += 256) {
    int ii = i + (i >> 5);
    sfw[ii] = fact[3 * F + i];
    sib[ii] = fact[4 * F + i];
    sbk[ii] = fact[5 * F + i];
  }
  __syncthreads();
  int gt  = blockIdx.x * 256 + threadIdx.x;
  int row = gt / LPR;
  int j   = gt % LPR;                          // lane-in-row, contiguous in wave
  int k0  = j * 32;
  const size_t rb = (size_t)row * F;

  // chunk x
  float xc[32];
  if (INF32) {
    const float* xr = (const float*)X + rb + k0;
    #pragma unroll
    for (int t = 0; t < 8; ++t) {
      float4 v = ((const float4*)xr)[t];
      xc[4*t] = v.x; xc[4*t+1] = v.y; xc[4*t+2] = v.z; xc[4*t+3] = v.w;
    }
  } else {
    const uint16_t* xr = (const uint16_t*)X + rb + k0;
    #pragma unroll
    for (int t = 0; t < 4; ++t) {
      U4 in; in.v = ((const uint4*)xr)[t];
      #pragma unroll
      for (int s = 0; s < 8; ++s) xc[8*t+s] = bf2f(in.s[s]);
    }
  }

  // forward: 16-step halo warm-up, then own 32
  float dp = 0.0f;
  if (j > 0) {
    float xw[16];
    if (INF32) {
      const float* xr = (const float*)X + rb + k0 - 16;
      #pragma unroll
      for (int t = 0; t < 4; ++t) {
        float4 v = ((const float4*)xr)[t];
        xw[4*t] = v.x; xw[4*t+1] = v.y; xw[4*t+2] = v.z; xw[4*t+3] = v.w;
      }
    } else {
      const uint16_t* xr = (const uint16_t*)X + rb + k0 - 16;
      #pragma unroll
      for (int t = 0; t < 2; ++t) {
        U4 in; in.v = ((const uint4*)xr)[t];
        #pragma unroll
        for (int s = 0; s < 8; ++s) xw[8*t+s] = bf2f(in.s[s]);
      }
    }
    #pragma unroll
    for (int t = 0; t < 16; ++t) {
      int k = k0 - 16 + t;
      dp = fmaf(-sfw[k + (k >> 5)], dp, xw[t]);
    }
  }
  float dpv[32];
  #pragma unroll
  for (int t = 0; t < 32; ++t) {
    int k = k0 + t;
    dp = fmaf(-sfw[k + (k >> 5)], dp, xc[t]);
    dpv[t] = dp;
  }

  // backward: halo dp from lane+1 (shfl must run on all lanes), 16-step warm-up
  float wdp[16];
  #pragma unroll
  for (int t = 0; t < 16; ++t) wdp[t] = __shfl_down(dpv[t], 1);
  float yn = 0.0f;
  if (j < LPR - 1) {
    #pragma unroll
    for (int t = 15; t >= 0; --t) {
      int k = k0 + 32 + t;
      int kk = k + (k >> 5);
      yn = fmaf(-sbk[kk], yn, wdp[t] * sib[kk]);
    }
  }
  U4 out[4];
  #pragma unroll
  for (int t = 31; t >= 0; --t) {
    int k = k0 + t;
    int kk = k + (k >> 5);
    yn = fmaf(-sbk[kk], yn, dpv[t] * sib[kk]);
    out[t >> 3].s[t & 7] = f2bf(yn);
  }
  uint16_t* yr = Y + rb + k0;
  #pragma unroll
  for (int t = 0; t < 4; ++t) ((uint4*)yr)[t] = out[t].v;
}

// ---- bf16 GEMM, C[m][n] = sum_k A[m][k]*Bw[n][k] (both K-major, bf16), m97 structure.
__device__ __forceinline__ void gl_lds16(const uint16_t* g, uint16_t* l) {
  __builtin_amdgcn_global_load_lds((const __attribute__((address_space(1))) void*)g,
                                   (__attribute__((address_space(3))) void*)l, 16, 0, 0);
}

template<bool RELU, bool OUTF32>
__launch_bounds__(256, 1)
__global__ void gemm_bt(const uint16_t* __restrict__ A, const uint16_t* __restrict__ Bw,
                        const uint16_t* __restrict__ bias, void* __restrict__ Cout,
                        int N, int K, const int* flag, int mode) {
  if (*flag != mode) return;
  __shared__ uint16_t As[128 * 32];
  __shared__ uint16_t Bs[128 * 32];
  const int tid  = threadIdx.x;
  const int lane = tid & 63;
  const int wv   = tid >> 6;
  const int wm   = (wv >> 1) * 64;
  const int wn   = (wv & 1) * 64;
  const int rowA0 = blockIdx.x * 128;
  const int rowB0 = blockIdx.y * 128;
  const int r  = tid >> 2;
  const int kc = (tid & 3) * 8;
  const uint16_t* agp0 = A  + (size_t)(rowA0 + r) * K + kc;
  const uint16_t* agp1 = agp0 + (size_t)64 * K;
  const uint16_t* bgp0 = Bw + (size_t)(rowB0 + r) * K + kc;
  const uint16_t* bgp1 = bgp0 + (size_t)64 * K;
  const int wbase = (tid & ~63) * 8;
  uint16_t* asl0 = As + wbase;
  uint16_t* asl1 = As + 2048 + wbase;
  uint16_t* bsl0 = Bs + wbase;
  uint16_t* bsl1 = Bs + 2048 + wbase;

  const int aoff = (wm + (lane & 15)) * 32 + (lane >> 4) * 8;
  const int boff = (wn + (lane & 15)) * 32 + (lane >> 4) * 8;

  f32x4 acc[4][4] = {};

  for (int kt = 0; kt < K; kt += 32) {
    gl_lds16(agp0 + kt, asl0);
    gl_lds16(agp1 + kt, asl1);
    gl_lds16(bgp0 + kt, bsl0);
    gl_lds16(bgp1 + kt, bsl1);
    __syncthreads();
    bf16x8 af[4], bfr[4];
    #pragma unroll
    for (int i = 0; i < 4; ++i) af[i]  = *(const bf16x8*)(As + aoff + i * 512);
    #pragma unroll
    for (int j = 0; j < 4; ++j) bfr[j] = *(const bf16x8*)(Bs + boff + j * 512);
    #pragma unroll
    for (int i = 0; i < 4; ++i)
      #pragma unroll
      for (int j = 0; j < 4; ++j)
        acc[i][j] = __builtin_amdgcn_mfma_f32_16x16x32_bf16(af[i], bfr[j], acc[i][j], 0, 0, 0);
    __syncthreads();
  }

  // C/D layout: col = lane&15, row = (lane>>4)*4 + reg
  const int ccol = lane & 15;
  const int crow = (lane >> 4) * 4;
  #pragma unroll
  for (int j = 0; j < 4; ++j) {
    int col = rowB0 + wn + j * 16 + ccol;
    float bv = bf2f(bias[col]);
    #pragma unroll
    for (int i = 0; i < 4; ++i) {
      int row0 = rowA0 + wm + i * 16 + crow;
      #pragma unroll
      for (int rr = 0; rr < 4; ++rr) {
        float v = acc[i][j][rr] + bv;
        if (RELU) v = fmaxf(v, 0.0f);
        size_t idx = (size_t)(row0 + rr) * N + col;
        if (OUTF32) ((float*)Cout)[idx]    = v;
        else        ((uint16_t*)Cout)[idx] = f2bf(v);
      }
    }
  }
}

extern "C" void kernel_launch(void* const* d_in, const int* in_sizes, int n_in,
                              void* d_out, int out_size, void* d_ws, size_t ws_size,
                              hipStream_t stream) {
  const void* x  = d_in[0];
  const void* d1 = d_in[1];
  const void* l1 = d_in[2];
  const void* u1 = d_in[3];
  const void* W1 = d_in[4];
  const void* b1 = d_in[5];
  const void* d2 = d_in[6];
  const void* l2 = d_in[7];
  const void* u2 = d_in[8];
  const void* W2 = d_in[9];
  const void* b2 = d_in[10];

  char* ws = (char*)d_ws;
  int*      flag = (int*)ws;
  float*    f1   = (float*)(ws + 256);            // 6*512*4 = 12 KB
  float*    f2   = (float*)(ws + (64 << 10));     // 6*2048*4 = 48 KB (ends 112 KB)
  uint16_t* b1b  = (uint16_t*)(ws + (128 << 10));
  uint16_t* b2b  = (uint16_t*)(ws + (136 << 10));
  uint16_t* W1b  = (uint16_t*)(ws + (1 << 20));                     // 2 MB
  uint16_t* W2b  = (uint16_t*)(ws + (3 << 20));                     // 2 MB
  uint16_t* A1   = (uint16_t*)(ws + ((size_t)8 << 20));             // 32 MB
  uint16_t* H1   = (uint16_t*)(ws + ((size_t)40 << 20));            // 128 MB, ends at 168 MB

  sniff_kernel<<<1, 64, 0, stream>>>((const uint16_t*)x, flag);

  {
    int quads = (F2 * F1) / 2 + F2 / 4 + NOUT / 4;
    conv_all<<<(quads + 255) / 256, 256, 0, stream>>>(
        (const float*)W1, (const float*)W2, (const float*)b1, (const float*)b2,
        W1b, W2b, b1b, b2b, flag);
  }

  prep_fused<false><<<2, 256, 0, stream>>>(d1, l1, u1, d2, l2, u2, f1, f2, flag, 0);
  prep_fused<true ><<<2, 256, 0, stream>>>(d1, l1, u1, d2, l2, u2, f1, f2, flag, 1);

  // F1 solve: 16 lanes/row, 16 rows/block -> 2048 blocks
  solve_fused<F1, false><<<R_ROWS / 16, 256, 0, stream>>>(x, A1, f1, flag, 0);
  solve_fused<F1, true ><<<R_ROWS / 16, 256, 0, stream>>>(x, A1, f1, flag, 1);

  gemm_bt<true, false><<<dim3(R_ROWS / 128, F2 / 128), 256, 0, stream>>>(
      A1, (const uint16_t*)W1, (const uint16_t*)b1, H1, F2, F1, flag, 0);
  gemm_bt<true, false><<<dim3(R_ROWS / 128, F2 / 128), 256, 0, stream>>>(
      A1, W1b, b1b, H1, F2, F1, flag, 1);

  // F2 solve: 64 lanes/row, 4 rows/block -> 8192 blocks, in-place on H1
  solve_fused<F2, false><<<R_ROWS / 4, 256, 0, stream>>>(H1, H1, f2, flag, -1);

  gemm_bt<false, false><<<dim3(R_ROWS / 128, NOUT / 128), 256, 0, stream>>>(
      H1, (const uint16_t*)W2, (const uint16_t*)b2, d_out, NOUT, F2, flag, 0);
  gemm_bt<false, true ><<<dim3(R_ROWS / 128, NOUT / 128), 256, 0, stream>>>(
      H1, W2b, b2b, d_out, NOUT, F2, flag, 1);
}

// Round 5
// 502.123 us; speedup vs baseline: 1.8033x; 1.0407x over previous
//
#include <hip/hip_runtime.h>
#include <cstdint>

#define R_ROWS 32768
#define F1 512
#define F2 2048
#define NOUT 512

typedef __bf16 bf16x8 __attribute__((ext_vector_type(8)));
typedef float f32x4 __attribute__((ext_vector_type(4)));

__device__ __forceinline__ float bf2f(uint16_t b) {
  union { uint32_t u; float f; } v; v.u = ((uint32_t)b) << 16; return v.f;
}
__device__ __forceinline__ uint16_t f2bf(float f) {
  union { float f; uint32_t u; } v; v.f = f;
  uint32_t u = v.u;
  return (uint16_t)((u + 0x7fffu + ((u >> 16) & 1u)) >> 16);
}

union U4 { uint4 v; uint16_t s[8]; };

// ---- dtype sniffer: bf16 N(0,1) data has sane exponent fields in EVERY uint16;
// fp32 data reinterpreted as uint16 has ~79% insane exponents in the low halves.
__global__ void sniff_kernel(const uint16_t* x, int* flag) {
  if (threadIdx.x == 0) {
    int bad = 0;
    for (int i = 0; i < 64; ++i) {
      uint32_t e = (x[i] >> 7) & 0xFFu;
      if (e != 0u && (e < 90u || e > 141u)) bad++;
    }
    *flag = (bad >= 8) ? 1 : 0;  // 1 = fp32 world, 0 = bf16 world
  }
}

// ---- fp32 world only: convert W1, W2, b1, b2 to bf16 in one launch, 4 elems/thread.
__global__ void conv_all(const float* W1, const float* W2, const float* b1, const float* b2,
                         uint16_t* W1b, uint16_t* W2b, uint16_t* b1b, uint16_t* b2b,
                         const int* flag) {
  if (*flag != 1) return;
  const int NW = F2 * F1;                  // 1048576 (both W1 and W2)
  int q = blockIdx.x * blockDim.x + threadIdx.x;
  const float* src; uint16_t* dst; int base;
  if (q < NW / 4)                       { src = W1; dst = W1b; base = q; }
  else if (q < NW / 2)                  { src = W2; dst = W2b; base = q - NW / 4; }
  else if (q < NW / 2 + F2 / 4)         { src = b1; dst = b1b; base = q - NW / 2; }
  else if (q < NW / 2 + F2 / 4 + NOUT/4){ src = b2; dst = b2b; base = q - NW / 2 - F2 / 4; }
  else return;
  float4 v = ((const float4*)src)[base];
  ushort4 o;
  o.x = f2bf(v.x); o.y = f2bf(v.y); o.z = f2bf(v.z); o.w = f2bf(v.w);
  ((ushort4*)dst)[base] = o;
}

// ---- fused prep: softplus/tanh in parallel into LDS, sequential Thomas factorization
// from LDS (rcp chain), parallel writeback of [tu | w | invb | bk=tu*invb].
// fact global layout per matrix (floats): [diag | tl | tu | w | invb | bk].
__launch_bounds__(256)
__global__ void prep_fused(const void* d1, const void* l1, const void* u1,
                           const void* d2, const void* l2, const void* u2,
                           float* f1, float* f2, const int* flag) {
  const bool inf32 = (*flag == 1);
  const int F = blockIdx.x ? F2 : F1;
  float* base = blockIdx.x ? f2 : f1;
  const void* dp = blockIdx.x ? d2 : d1;
  const void* lp = blockIdx.x ? l2 : l1;
  const void* up = blockIdx.x ? u2 : u1;

  __shared__ float sdiag[F2], stl[F2], stu[F2], sfw[F2], sib[F2];

  for (int i = threadIdx.x; i < F; i += 256) {
    float dv = inf32 ? ((const float*)dp)[i] : bf2f(((const uint16_t*)dp)[i]);
    sdiag[i] = log1pf(expf(dv)) + 2.0f;
    bool in = i < F - 1;
    float lv = in ? (inf32 ? ((const float*)lp)[i] : bf2f(((const uint16_t*)lp)[i])) : 0.0f;
    float uv = in ? (inf32 ? ((const float*)up)[i] : bf2f(((const uint16_t*)up)[i])) : 0.0f;
    stl[i] = in ? tanhf(lv) : 0.0f;
    stu[i] = in ? tanhf(uv) : 0.0f;
  }
  __syncthreads();
  if (threadIdx.x == 0) {
    float ib = __builtin_amdgcn_rcpf(sdiag[0]);
    sfw[0] = 0.0f; sib[0] = ib;
    #pragma unroll 8
    for (int i = 1; i < F; ++i) {
      float w = stl[i - 1] * ib;
      float b = fmaf(-w, stu[i - 1], sdiag[i]);
      ib = __builtin_amdgcn_rcpf(b);
      sfw[i] = w; sib[i] = ib;
    }
  }
  __syncthreads();
  for (int i = threadIdx.x; i < F; i += 256) {
    base[2 * F + i] = stu[i];
    base[3 * F + i] = sfw[i];
    base[4 * F + i] = sib[i];
    base[5 * F + i] = stu[i] * sib[i];
  }
}

// ---- chunk-parallel Thomas solve. Lane owns 32 elements of F; 16-element halo
// warm-up exploits the recurrence's exponential decay (|coef| <= ~0.03).
// allow_f32: input may be fp32 (selected by flag); output always bf16.
// In-place X==Y safe: halo interactions intra-wave, loads precede stores.
template<int F>
__launch_bounds__(256)
__global__ void solve_fused(const void* X, uint16_t* Y, const float* fact,
                            const int* flag, int allow_f32) {
  const bool inf32 = allow_f32 && (*flag == 1);
  constexpr int LPR = F / 32;                  // lanes per row (16 or 64)
  constexpr int FP = F + (F >> 5);             // padded coeff size
  __shared__ float sfw[FP], sib[FP], sbk[FP];
  for (int i = threadIdx.x; i < F; i += 256) {
    int ii = i + (i >> 5);
    sfw[ii] = fact[3 * F + i];
    sib[ii] = fact[4 * F + i];
    sbk[ii] = fact[5 * F + i];
  }
  __syncthreads();
  int gt  = blockIdx.x * 256 + threadIdx.x;
  int row = gt / LPR;
  int j   = gt % LPR;                          // lane-in-row, contiguous in wave
  int k0  = j * 32;
  const size_t rb = (size_t)row * F;

  // chunk x
  float xc[32];
  if (inf32) {
    const float* xr = (const float*)X + rb + k0;
    #pragma unroll
    for (int t = 0; t < 8; ++t) {
      float4 v = ((const float4*)xr)[t];
      xc[4*t] = v.x; xc[4*t+1] = v.y; xc[4*t+2] = v.z; xc[4*t+3] = v.w;
    }
  } else {
    const uint16_t* xr = (const uint16_t*)X + rb + k0;
    #pragma unroll
    for (int t = 0; t < 4; ++t) {
      U4 in; in.v = ((const uint4*)xr)[t];
      #pragma unroll
      for (int s = 0; s < 8; ++s) xc[8*t+s] = bf2f(in.s[s]);
    }
  }

  // forward: 16-step halo warm-up, then own 32
  float dp = 0.0f;
  if (j > 0) {
    float xw[16];
    if (inf32) {
      const float* xr = (const float*)X + rb + k0 - 16;
      #pragma unroll
      for (int t = 0; t < 4; ++t) {
        float4 v = ((const float4*)xr)[t];
        xw[4*t] = v.x; xw[4*t+1] = v.y; xw[4*t+2] = v.z; xw[4*t+3] = v.w;
      }
    } else {
      const uint16_t* xr = (const uint16_t*)X + rb + k0 - 16;
      #pragma unroll
      for (int t = 0; t < 2; ++t) {
        U4 in; in.v = ((const uint4*)xr)[t];
        #pragma unroll
        for (int s = 0; s < 8; ++s) xw[8*t+s] = bf2f(in.s[s]);
      }
    }
    #pragma unroll
    for (int t = 0; t < 16; ++t) {
      int k = k0 - 16 + t;
      dp = fmaf(-sfw[k + (k >> 5)], dp, xw[t]);
    }
  }
  float dpv[32];
  #pragma unroll
  for (int t = 0; t < 32; ++t) {
    int k = k0 + t;
    dp = fmaf(-sfw[k + (k >> 5)], dp, xc[t]);
    dpv[t] = dp;
  }

  // backward: halo dp from lane+1 (shfl must run on all lanes), 16-step warm-up
  float wdp[16];
  #pragma unroll
  for (int t = 0; t < 16; ++t) wdp[t] = __shfl_down(dpv[t], 1);
  float yn = 0.0f;
  if (j < LPR - 1) {
    #pragma unroll
    for (int t = 15; t >= 0; --t) {
      int k = k0 + 32 + t;
      int kk = k + (k >> 5);
      yn = fmaf(-sbk[kk], yn, wdp[t] * sib[kk]);
    }
  }
  U4 out[4];
  #pragma unroll
  for (int t = 31; t >= 0; --t) {
    int k = k0 + t;
    int kk = k + (k >> 5);
    yn = fmaf(-sbk[kk], yn, dpv[t] * sib[kk]);
    out[t >> 3].s[t & 7] = f2bf(yn);
  }
  uint16_t* yr = Y + rb + k0;
  #pragma unroll
  for (int t = 0; t < 4; ++t) ((uint4*)yr)[t] = out[t].v;
}

// ---- bf16 GEMM, C[m][n] = sum_k A[m][k]*Bw[n][k] (both K-major, bf16).
// BK=64 (32 MFMA per barrier pair), XOR-swizzled LDS (conflict-free b128 frag
// reads at 128B row stride), grid x = N-tiles (fast) for A-tile L2 reuse.
// LDS[row][pos] holds global chunk (pos ^ (row&7)); staging gathers per-lane
// global chunk c = (t&7)^((t>>3)&7) so dest stays uniform-base + lane*16.
__device__ __forceinline__ void gl_lds16(const uint16_t* g, uint16_t* l) {
  __builtin_amdgcn_global_load_lds((const __attribute__((address_space(1))) void*)g,
                                   (__attribute__((address_space(3))) void*)l, 16, 0, 0);
}

template<bool RELU, bool FINAL>
__launch_bounds__(256, 1)
__global__ void gemm_bt(const uint16_t* __restrict__ A,
                        const uint16_t* __restrict__ Bw0, const uint16_t* __restrict__ Bw1,
                        const uint16_t* __restrict__ bias0, const uint16_t* __restrict__ bias1,
                        void* __restrict__ Cout, int N, int K, const int* flag) {
  const int f = *flag;
  const uint16_t* Bw   = f ? Bw1 : Bw0;
  const uint16_t* bias = f ? bias1 : bias0;

  __shared__ __align__(16) uint16_t As[128 * 64];
  __shared__ __align__(16) uint16_t Bs[128 * 64];
  const int tid  = threadIdx.x;
  const int lane = tid & 63;
  const int wv   = tid >> 6;
  const int wm   = (wv >> 1) * 64;
  const int wn   = (wv & 1) * 64;
  const int rowA0 = blockIdx.y * 128;   // M tile
  const int rowB0 = blockIdx.x * 128;   // N tile (fast-varying for A reuse)

  // staging: thread t -> row r = t>>3 (+32 per instr), chunk c = (t&7)^((t>>3)&7)
  const int r = tid >> 3;
  const int c = (tid & 7) ^ (r & 7);
  const uint16_t* agb = A  + (size_t)(rowA0 + r) * K + c * 8;
  const uint16_t* bgb = Bw + (size_t)(rowB0 + r) * K + c * 8;
  const int wof = wv * 512;             // LDS elems, uniform per wave

  // fragment offsets (elems): row stride 64, chunk pos = (q ^ (lane&7))*8
  const int lm = lane & 15;
  const int l7 = lane & 7;
  const int pos0 = ((lane >> 4) ^ l7) << 3;
  const int aoff0 = (wm + lm) * 64 + pos0;
  const int aoff1 = (wm + lm) * 64 + (pos0 ^ 32);
  const int boff0 = (wn + lm) * 64 + pos0;
  const int boff1 = (wn + lm) * 64 + (pos0 ^ 32);

  f32x4 acc[4][4] = {};

  for (int kt = 0; kt < K; kt += 64) {
    #pragma unroll
    for (int i = 0; i < 4; ++i) gl_lds16(agb + (size_t)i * 32 * K + kt, As + i * 2048 + wof);
    #pragma unroll
    for (int i = 0; i < 4; ++i) gl_lds16(bgb + (size_t)i * 32 * K + kt, Bs + i * 2048 + wof);
    __syncthreads();
    bf16x8 af[4], bfr[4];
    #pragma unroll
    for (int i = 0; i < 4; ++i) af[i]  = *(const bf16x8*)(As + aoff0 + i * 1024);
    #pragma unroll
    for (int j = 0; j < 4; ++j) bfr[j] = *(const bf16x8*)(Bs + boff0 + j * 1024);
    #pragma unroll
    for (int i = 0; i < 4; ++i)
      #pragma unroll
      for (int j = 0; j < 4; ++j)
        acc[i][j] = __builtin_amdgcn_mfma_f32_16x16x32_bf16(af[i], bfr[j], acc[i][j], 0, 0, 0);
    #pragma unroll
    for (int i = 0; i < 4; ++i) af[i]  = *(const bf16x8*)(As + aoff1 + i * 1024);
    #pragma unroll
    for (int j = 0; j < 4; ++j) bfr[j] = *(const bf16x8*)(Bs + boff1 + j * 1024);
    #pragma unroll
    for (int i = 0; i < 4; ++i)
      #pragma unroll
      for (int j = 0; j < 4; ++j)
        acc[i][j] = __builtin_amdgcn_mfma_f32_16x16x32_bf16(af[i], bfr[j], acc[i][j], 0, 0, 0);
    __syncthreads();
  }

  // C/D layout: col = lane&15, row = (lane>>4)*4 + reg
  const bool outf32 = FINAL && (f != 0);
  const int ccol = lm;
  const int crow = (lane >> 4) * 4;
  #pragma unroll
  for (int j = 0; j < 4; ++j) {
    int col = rowB0 + wn + j * 16 + ccol;
    float bv = bf2f(bias[col]);
    #pragma unroll
    for (int i = 0; i < 4; ++i) {
      int row0 = rowA0 + wm + i * 16 + crow;
      #pragma unroll
      for (int rr = 0; rr < 4; ++rr) {
        float v = acc[i][j][rr] + bv;
        if (RELU) v = fmaxf(v, 0.0f);
        size_t idx = (size_t)(row0 + rr) * N + col;
        if (outf32) ((float*)Cout)[idx]    = v;
        else        ((uint16_t*)Cout)[idx] = f2bf(v);
      }
    }
  }
}

extern "C" void kernel_launch(void* const* d_in, const int* in_sizes, int n_in,
                              void* d_out, int out_size, void* d_ws, size_t ws_size,
                              hipStream_t stream) {
  const void* x  = d_in[0];
  const void* d1 = d_in[1];
  const void* l1 = d_in[2];
  const void* u1 = d_in[3];
  const void* W1 = d_in[4];
  const void* b1 = d_in[5];
  const void* d2 = d_in[6];
  const void* l2 = d_in[7];
  const void* u2 = d_in[8];
  const void* W2 = d_in[9];
  const void* b2 = d_in[10];

  char* ws = (char*)d_ws;
  int*      flag = (int*)ws;
  float*    f1   = (float*)(ws + 256);            // 6*512*4 = 12 KB
  float*    f2   = (float*)(ws + (64 << 10));     // 6*2048*4 = 48 KB
  uint16_t* b1b  = (uint16_t*)(ws + (128 << 10));
  uint16_t* b2b  = (uint16_t*)(ws + (136 << 10));
  uint16_t* W1b  = (uint16_t*)(ws + (1 << 20));                     // 2 MB
  uint16_t* W2b  = (uint16_t*)(ws + (3 << 20));                     // 2 MB
  uint16_t* A1   = (uint16_t*)(ws + ((size_t)8 << 20));             // 32 MB
  uint16_t* H1   = (uint16_t*)(ws + ((size_t)40 << 20));            // 128 MB, ends at 168 MB

  sniff_kernel<<<1, 64, 0, stream>>>((const uint16_t*)x, flag);

  {
    int quads = (F2 * F1) / 2 + F2 / 4 + NOUT / 4;
    conv_all<<<(quads + 255) / 256, 256, 0, stream>>>(
        (const float*)W1, (const float*)W2, (const float*)b1, (const float*)b2,
        W1b, W2b, b1b, b2b, flag);
  }

  prep_fused<<<2, 256, 0, stream>>>(d1, l1, u1, d2, l2, u2, f1, f2, flag);

  // F1 solve: 16 lanes/row, 16 rows/block
  solve_fused<F1><<<R_ROWS / 16, 256, 0, stream>>>(x, A1, f1, flag, 1);

  gemm_bt<true, false><<<dim3(F2 / 128, R_ROWS / 128), 256, 0, stream>>>(
      A1, (const uint16_t*)W1, W1b, (const uint16_t*)b1, b1b, H1, F2, F1, flag);

  // F2 solve: 64 lanes/row, 4 rows/block, in-place on H1
  solve_fused<F2><<<R_ROWS / 4, 256, 0, stream>>>(H1, H1, f2, flag, 0);

  gemm_bt<false, true><<<dim3(NOUT / 128, R_ROWS / 128), 256, 0, stream>>>(
      H1, (const uint16_t*)W2, W2b, (const uint16_t*)b2, b2b, d_out, NOUT, F2, flag);
}

// Round 6
// 468.514 us; speedup vs baseline: 1.9326x; 1.0717x over previous
//
#include <hip/hip_runtime.h>
#include <cstdint>

#define R_ROWS 32768
#define F1 512
#define F2 2048
#define NOUT 512

typedef __bf16 bf16x8 __attribute__((ext_vector_type(8)));
typedef float f32x4 __attribute__((ext_vector_type(4)));

__device__ __forceinline__ float bf2f(uint16_t b) {
  union { uint32_t u; float f; } v; v.u = ((uint32_t)b) << 16; return v.f;
}
__device__ __forceinline__ uint16_t f2bf(float f) {
  union { float f; uint32_t u; } v; v.f = f;
  uint32_t u = v.u;
  return (uint16_t)((u + 0x7fffu + ((u >> 16) & 1u)) >> 16);
}

union U4 { uint4 v; uint16_t s[8]; };

// ---- dtype sniffer: bf16 N(0,1) data has sane exponent fields in EVERY uint16;
// fp32 data reinterpreted as uint16 has ~79% insane exponents in the low halves.
__global__ void sniff_kernel(const uint16_t* x, int* flag) {
  if (threadIdx.x == 0) {
    int bad = 0;
    for (int i = 0; i < 64; ++i) {
      uint32_t e = (x[i] >> 7) & 0xFFu;
      if (e != 0u && (e < 90u || e > 141u)) bad++;
    }
    *flag = (bad >= 8) ? 1 : 0;  // 1 = fp32 world, 0 = bf16 world
  }
}

// ---- fp32 world only: convert W1, W2, b1, b2 to bf16 in one launch, 4 elems/thread.
__global__ void conv_all(const float* W1, const float* W2, const float* b1, const float* b2,
                         uint16_t* W1b, uint16_t* W2b, uint16_t* b1b, uint16_t* b2b,
                         const int* flag) {
  if (*flag != 1) return;
  const int NW = F2 * F1;                  // 1048576 (both W1 and W2)
  int q = blockIdx.x * blockDim.x + threadIdx.x;
  const float* src; uint16_t* dst; int base;
  if (q < NW / 4)                       { src = W1; dst = W1b; base = q; }
  else if (q < NW / 2)                  { src = W2; dst = W2b; base = q - NW / 4; }
  else if (q < NW / 2 + F2 / 4)         { src = b1; dst = b1b; base = q - NW / 2; }
  else if (q < NW / 2 + F2 / 4 + NOUT/4){ src = b2; dst = b2b; base = q - NW / 2 - F2 / 4; }
  else return;
  float4 v = ((const float4*)src)[base];
  ushort4 o;
  o.x = f2bf(v.x); o.y = f2bf(v.y); o.z = f2bf(v.z); o.w = f2bf(v.w);
  ((ushort4*)dst)[base] = o;
}

// ---- fused prep: softplus/tanh in parallel into LDS, sequential Thomas factorization
// from LDS (rcp chain), parallel writeback of [tu | w | invb | bk=tu*invb].
// fact global layout per matrix (floats): [diag | tl | tu | w | invb | bk].
__launch_bounds__(256)
__global__ void prep_fused(const void* d1, const void* l1, const void* u1,
                           const void* d2, const void* l2, const void* u2,
                           float* f1, float* f2, const int* flag) {
  const bool inf32 = (*flag == 1);
  const int F = blockIdx.x ? F2 : F1;
  float* base = blockIdx.x ? f2 : f1;
  const void* dp = blockIdx.x ? d2 : d1;
  const void* lp = blockIdx.x ? l2 : l1;
  const void* up = blockIdx.x ? u2 : u1;

  __shared__ float sdiag[F2], stl[F2], stu[F2], sfw[F2], sib[F2];

  for (int i = threadIdx.x; i < F; i += 256) {
    float dv = inf32 ? ((const float*)dp)[i] : bf2f(((const uint16_t*)dp)[i]);
    sdiag[i] = log1pf(expf(dv)) + 2.0f;
    bool in = i < F - 1;
    float lv = in ? (inf32 ? ((const float*)lp)[i] : bf2f(((const uint16_t*)lp)[i])) : 0.0f;
    float uv = in ? (inf32 ? ((const float*)up)[i] : bf2f(((const uint16_t*)up)[i])) : 0.0f;
    stl[i] = in ? tanhf(lv) : 0.0f;
    stu[i] = in ? tanhf(uv) : 0.0f;
  }
  __syncthreads();
  if (threadIdx.x == 0) {
    float ib = __builtin_amdgcn_rcpf(sdiag[0]);
    sfw[0] = 0.0f; sib[0] = ib;
    #pragma unroll 8
    for (int i = 1; i < F; ++i) {
      float w = stl[i - 1] * ib;
      float b = fmaf(-w, stu[i - 1], sdiag[i]);
      ib = __builtin_amdgcn_rcpf(b);
      sfw[i] = w; sib[i] = ib;
    }
  }
  __syncthreads();
  for (int i = threadIdx.x; i < F; i += 256) {
    base[2 * F + i] = stu[i];
    base[3 * F + i] = sfw[i];
    base[4 * F + i] = sib[i];
    base[5 * F + i] = stu[i] * sib[i];
  }
}

// ---- chunk-parallel Thomas solve. Lane owns 32 elements of F; 16-element halo
// warm-up exploits the recurrence's exponential decay (|coef| <= ~0.03).
// Output staged through LDS so global stores are fully dense (fixes the 2x
// partial-cacheline write amplification seen in r3: WRITE 247MB vs 128 ideal).
// In-place X==Y safe: all input loads complete (consumed into LDS) before the
// post-barrier copy-out issues any store; blocks touch disjoint rows.
template<int F>
__launch_bounds__(256)
__global__ void solve_fused(const void* X, uint16_t* Y, const float* fact,
                            const int* flag, int allow_f32) {
  const bool inf32 = allow_f32 && (*flag == 1);
  constexpr int LPR = F / 32;                  // lanes per row (16 or 64)
  constexpr int FP = F + (F >> 5);             // padded coeff size
  __shared__ float sfw[FP], sib[FP], sbk[FP];
  __shared__ uint4 sout[1024];                 // 256 threads * 32 elems = 16 KB
  for (int i = threadIdx.x; i < F; i += 256) {
    int ii = i + (i >> 5);
    sfw[ii] = fact[3 * F + i];
    sib[ii] = fact[4 * F + i];
    sbk[ii] = fact[5 * F + i];
  }
  __syncthreads();
  const int tid = threadIdx.x;
  int gt  = blockIdx.x * 256 + tid;
  int row = gt / LPR;
  int j   = gt % LPR;                          // lane-in-row, contiguous in wave
  int k0  = j * 32;
  const size_t rb = (size_t)row * F;

  // chunk x
  float xc[32];
  if (inf32) {
    const float* xr = (const float*)X + rb + k0;
    #pragma unroll
    for (int t = 0; t < 8; ++t) {
      float4 v = ((const float4*)xr)[t];
      xc[4*t] = v.x; xc[4*t+1] = v.y; xc[4*t+2] = v.z; xc[4*t+3] = v.w;
    }
  } else {
    const uint16_t* xr = (const uint16_t*)X + rb + k0;
    #pragma unroll
    for (int t = 0; t < 4; ++t) {
      U4 in; in.v = ((const uint4*)xr)[t];
      #pragma unroll
      for (int s = 0; s < 8; ++s) xc[8*t+s] = bf2f(in.s[s]);
    }
  }

  // forward: 16-step halo warm-up, then own 32
  float dp = 0.0f;
  if (j > 0) {
    float xw[16];
    if (inf32) {
      const float* xr = (const float*)X + rb + k0 - 16;
      #pragma unroll
      for (int t = 0; t < 4; ++t) {
        float4 v = ((const float4*)xr)[t];
        xw[4*t] = v.x; xw[4*t+1] = v.y; xw[4*t+2] = v.z; xw[4*t+3] = v.w;
      }
    } else {
      const uint16_t* xr = (const uint16_t*)X + rb + k0 - 16;
      #pragma unroll
      for (int t = 0; t < 2; ++t) {
        U4 in; in.v = ((const uint4*)xr)[t];
        #pragma unroll
        for (int s = 0; s < 8; ++s) xw[8*t+s] = bf2f(in.s[s]);
      }
    }
    #pragma unroll
    for (int t = 0; t < 16; ++t) {
      int k = k0 - 16 + t;
      dp = fmaf(-sfw[k + (k >> 5)], dp, xw[t]);
    }
  }
  float dpv[32];
  #pragma unroll
  for (int t = 0; t < 32; ++t) {
    int k = k0 + t;
    dp = fmaf(-sfw[k + (k >> 5)], dp, xc[t]);
    dpv[t] = dp;
  }

  // backward: halo dp from lane+1 (shfl must run on all lanes), 16-step warm-up
  float wdp[16];
  #pragma unroll
  for (int t = 0; t < 16; ++t) wdp[t] = __shfl_down(dpv[t], 1);
  float yn = 0.0f;
  if (j < LPR - 1) {
    #pragma unroll
    for (int t = 15; t >= 0; --t) {
      int k = k0 + 32 + t;
      int kk = k + (k >> 5);
      yn = fmaf(-sbk[kk], yn, wdp[t] * sib[kk]);
    }
  }
  U4 out[4];
  #pragma unroll
  for (int t = 31; t >= 0; --t) {
    int k = k0 + t;
    int kk = k + (k >> 5);
    yn = fmaf(-sbk[kk], yn, dpv[t] * sib[kk]);
    out[t >> 3].s[t & 7] = f2bf(yn);
  }
  // stage to LDS; block's 8192 elems are contiguous: elem_off = tid*32 + t*8
  #pragma unroll
  for (int t = 0; t < 4; ++t) sout[tid * 4 + t] = out[t].v;
  __syncthreads();
  uint4* yg = (uint4*)Y + (size_t)blockIdx.x * 1024;
  #pragma unroll
  for (int i = 0; i < 4; ++i) yg[i * 256 + tid] = sout[i * 256 + tid];
}

// ---- bf16 GEMM, C[m][n] = sum_k A[m][k]*Bw[n][k] (both K-major, bf16).
// BK=64 (32 MFMA per barrier pair), XOR-swizzled LDS (conflict-free b128 frag
// reads), 1D grid with explicit XCD swizzle: b%8 = XCD (HW round-robin), all
// NT n-tiles of one m-tile land consecutively on ONE XCD -> A-tile served from
// that XCD's L2, A fetched ~once from HBM (r5 showed 2x+ A refetch without).
__device__ __forceinline__ void gl_lds16(const uint16_t* g, uint16_t* l) {
  __builtin_amdgcn_global_load_lds((const __attribute__((address_space(1))) void*)g,
                                   (__attribute__((address_space(3))) void*)l, 16, 0, 0);
}

template<bool RELU, bool FINAL, int NT>
__launch_bounds__(256, 1)
__global__ void gemm_bt(const uint16_t* __restrict__ A,
                        const uint16_t* __restrict__ Bw0, const uint16_t* __restrict__ Bw1,
                        const uint16_t* __restrict__ bias0, const uint16_t* __restrict__ bias1,
                        void* __restrict__ Cout, int N, int K, const int* flag) {
  const int f = *flag;
  const uint16_t* Bw   = f ? Bw1 : Bw0;
  const uint16_t* bias = f ? bias1 : bias0;

  __shared__ __align__(16) uint16_t As[128 * 64];
  __shared__ __align__(16) uint16_t Bs[128 * 64];
  const int tid  = threadIdx.x;
  const int lane = tid & 63;
  const int wv   = tid >> 6;
  const int wm   = (wv >> 1) * 64;
  const int wn   = (wv & 1) * 64;
  // XCD swizzle: x = XCD, g = slot within XCD; NT n-tiles per m-tile, m-tiles
  // strided by 8 across XCDs.
  const int b = blockIdx.x;
  const int x = b & 7;
  const int g = b >> 3;
  const int n = g & (NT - 1);
  const int m = (g / NT) * 8 + x;
  const int rowA0 = m * 128;
  const int rowB0 = n * 128;

  // staging: thread t -> row r = t>>3 (+32 per instr), chunk c = (t&7)^((t>>3)&7)
  const int r = tid >> 3;
  const int c = (tid & 7) ^ (r & 7);
  const uint16_t* agb = A  + (size_t)(rowA0 + r) * K + c * 8;
  const uint16_t* bgb = Bw + (size_t)(rowB0 + r) * K + c * 8;
  const int wof = wv * 512;             // LDS elems, uniform per wave

  // fragment offsets (elems): row stride 64, chunk pos = (q ^ (lane&7))*8
  const int lm = lane & 15;
  const int l7 = lane & 7;
  const int pos0 = ((lane >> 4) ^ l7) << 3;
  const int aoff0 = (wm + lm) * 64 + pos0;
  const int aoff1 = (wm + lm) * 64 + (pos0 ^ 32);
  const int boff0 = (wn + lm) * 64 + pos0;
  const int boff1 = (wn + lm) * 64 + (pos0 ^ 32);

  f32x4 acc[4][4] = {};

  for (int kt = 0; kt < K; kt += 64) {
    #pragma unroll
    for (int i = 0; i < 4; ++i) gl_lds16(agb + (size_t)i * 32 * K + kt, As + i * 2048 + wof);
    #pragma unroll
    for (int i = 0; i < 4; ++i) gl_lds16(bgb + (size_t)i * 32 * K + kt, Bs + i * 2048 + wof);
    __syncthreads();
    bf16x8 af[4], bfr[4];
    #pragma unroll
    for (int i = 0; i < 4; ++i) af[i]  = *(const bf16x8*)(As + aoff0 + i * 1024);
    #pragma unroll
    for (int j = 0; j < 4; ++j) bfr[j] = *(const bf16x8*)(Bs + boff0 + j * 1024);
    #pragma unroll
    for (int i = 0; i < 4; ++i)
      #pragma unroll
      for (int j = 0; j < 4; ++j)
        acc[i][j] = __builtin_amdgcn_mfma_f32_16x16x32_bf16(af[i], bfr[j], acc[i][j], 0, 0, 0);
    #pragma unroll
    for (int i = 0; i < 4; ++i) af[i]  = *(const bf16x8*)(As + aoff1 + i * 1024);
    #pragma unroll
    for (int j = 0; j < 4; ++j) bfr[j] = *(const bf16x8*)(Bs + boff1 + j * 1024);
    #pragma unroll
    for (int i = 0; i < 4; ++i)
      #pragma unroll
      for (int j = 0; j < 4; ++j)
        acc[i][j] = __builtin_amdgcn_mfma_f32_16x16x32_bf16(af[i], bfr[j], acc[i][j], 0, 0, 0);
    __syncthreads();
  }

  // C/D layout: col = lane&15, row = (lane>>4)*4 + reg
  const bool outf32 = FINAL && (f != 0);
  const int ccol = lm;
  const int crow = (lane >> 4) * 4;
  #pragma unroll
  for (int j = 0; j < 4; ++j) {
    int col = rowB0 + wn + j * 16 + ccol;
    float bv = bf2f(bias[col]);
    #pragma unroll
    for (int i = 0; i < 4; ++i) {
      int row0 = rowA0 + wm + i * 16 + crow;
      #pragma unroll
      for (int rr = 0; rr < 4; ++rr) {
        float v = acc[i][j][rr] + bv;
        if (RELU) v = fmaxf(v, 0.0f);
        size_t idx = (size_t)(row0 + rr) * N + col;
        if (outf32) ((float*)Cout)[idx]    = v;
        else        ((uint16_t*)Cout)[idx] = f2bf(v);
      }
    }
  }
}

extern "C" void kernel_launch(void* const* d_in, const int* in_sizes, int n_in,
                              void* d_out, int out_size, void* d_ws, size_t ws_size,
                              hipStream_t stream) {
  const void* x  = d_in[0];
  const void* d1 = d_in[1];
  const void* l1 = d_in[2];
  const void* u1 = d_in[3];
  const void* W1 = d_in[4];
  const void* b1 = d_in[5];
  const void* d2 = d_in[6];
  const void* l2 = d_in[7];
  const void* u2 = d_in[8];
  const void* W2 = d_in[9];
  const void* b2 = d_in[10];

  char* ws = (char*)d_ws;
  int*      flag = (int*)ws;
  float*    f1   = (float*)(ws + 256);            // 6*512*4 = 12 KB
  float*    f2   = (float*)(ws + (64 << 10));     // 6*2048*4 = 48 KB
  uint16_t* b1b  = (uint16_t*)(ws + (128 << 10));
  uint16_t* b2b  = (uint16_t*)(ws + (136 << 10));
  uint16_t* W1b  = (uint16_t*)(ws + (1 << 20));                     // 2 MB
  uint16_t* W2b  = (uint16_t*)(ws + (3 << 20));                     // 2 MB
  uint16_t* A1   = (uint16_t*)(ws + ((size_t)8 << 20));             // 32 MB
  uint16_t* H1   = (uint16_t*)(ws + ((size_t)40 << 20));            // 128 MB, ends at 168 MB

  sniff_kernel<<<1, 64, 0, stream>>>((const uint16_t*)x, flag);

  {
    int quads = (F2 * F1) / 2 + F2 / 4 + NOUT / 4;
    conv_all<<<(quads + 255) / 256, 256, 0, stream>>>(
        (const float*)W1, (const float*)W2, (const float*)b1, (const float*)b2,
        W1b, W2b, b1b, b2b, flag);
  }

  prep_fused<<<2, 256, 0, stream>>>(d1, l1, u1, d2, l2, u2, f1, f2, flag);

  // F1 solve: 16 lanes/row, 16 rows/block
  solve_fused<F1><<<R_ROWS / 16, 256, 0, stream>>>(x, A1, f1, flag, 1);

  // GEMM1: M=32768, N=2048 (NT=16), K=512 -> 4096 blocks
  gemm_bt<true, false, 16><<<4096, 256, 0, stream>>>(
      A1, (const uint16_t*)W1, W1b, (const uint16_t*)b1, b1b, H1, F2, F1, flag);

  // F2 solve: 64 lanes/row, 4 rows/block, in-place on H1
  solve_fused<F2><<<R_ROWS / 4, 256, 0, stream>>>(H1, H1, f2, flag, 0);

  // GEMM2: M=32768, N=512 (NT=4), K=2048 -> 1024 blocks
  gemm_bt<false, true, 4><<<1024, 256, 0, stream>>>(
      H1, (const uint16_t*)W2, W2b, (const uint16_t*)b2, b2b, d_out, NOUT, F2, flag);
}